// Round 3
// baseline (690.925 us; speedup 1.0000x reference)
//
#include <hip/hip_runtime.h>
#include <hip/hip_bf16.h>

#define ED 128
#define RR 8
#define KTOT (RR * ED)   // 1024
#define LDW 68           // LDS row stride in dwords (64 data + 4 pad)

typedef __attribute__((ext_vector_type(8))) short short8;   // 8 x bf16
typedef __attribute__((ext_vector_type(4))) float f32x4;    // MFMA accumulator

__device__ __forceinline__ unsigned short f2bf(float f){
  unsigned int u = __builtin_bit_cast(unsigned int, f);
  return (unsigned short)((u + 0x7fffu + ((u >> 16) & 1u)) >> 16);   // RNE
}
__device__ __forceinline__ float bf2f(unsigned int lo){
  return __builtin_bit_cast(float, lo << 16);
}

// ---- cast f32 -> bf16, 4 at a time ----
__global__ void cast_bf16_vec(const float4* __restrict__ in, ushort4* __restrict__ out, int n4){
  int stride = gridDim.x * blockDim.x;
  for (int i = blockIdx.x * blockDim.x + threadIdx.x; i < n4; i += stride){
    float4 v = in[i];
    ushort4 o;
    o.x = f2bf(v.x); o.y = f2bf(v.y); o.z = f2bf(v.z); o.w = f2bf(v.w);
    out[i] = o;
  }
}

// ---- w2t[j][r*128+kk] = W[r][j][kk]  (B^T layout for the MFMA fragment) ----
__global__ void build_w2t(const float* __restrict__ w, unsigned short* __restrict__ w2t){
  int idx = blockIdx.x * blockDim.x + threadIdx.x;     // over R*ED*ED = 131072
  int kk = idx & 127;
  int j  = (idx >> 7) & 127;
  int r  = idx >> 14;
  w2t[j * KTOT + r * ED + kk] = f2bf(w[idx]);
}

// ---- histogram over key = dst*8 + rel ----
__global__ void hist8(const int* __restrict__ rel, const int* __restrict__ dst,
                      int* __restrict__ rowcnt, int E){
  int stride = gridDim.x * blockDim.x;
  for (int i = blockIdx.x * blockDim.x + threadIdx.x; i < E; i += stride)
    atomicAdd(&rowcnt[(dst[i] << 3) | rel[i]], 1);
}

// ---- scan step 1: per-block (1024) sums ----
__launch_bounds__(1024)
__global__ void scan_block_sum(const int* __restrict__ rowcnt, int* __restrict__ bsum, int m){
  __shared__ int lds[16];
  int t = threadIdx.x;
  int idx = blockIdx.x * 1024 + t;
  int v = (idx < m) ? rowcnt[idx] : 0;
#pragma unroll
  for (int o = 32; o > 0; o >>= 1) v += __shfl_down(v, o);
  if ((t & 63) == 0) lds[t >> 6] = v;
  __syncthreads();
  if (t == 0){
    int s = 0;
#pragma unroll
    for (int w = 0; w < 16; ++w) s += lds[w];
    bsum[blockIdx.x] = s;
  }
}

// ---- scan step 2: serial exclusive scan of block sums (tiny) ----
__global__ void scan_bsum(const int* __restrict__ bsum, int* __restrict__ bscan,
                          int nb, int* __restrict__ total_out){
  if (threadIdx.x == 0 && blockIdx.x == 0){
    int acc = 0;
    for (int b = 0; b < nb; ++b){ bscan[b] = acc; acc += bsum[b]; }
    *total_out = acc;             // row_ptr[m]
  }
}

// ---- scan step 3: block-level exclusive scan + block offset; writes ptr AND cursor ----
__launch_bounds__(1024)
__global__ void scan_final(const int* __restrict__ rowcnt, const int* __restrict__ bscan,
                           int* __restrict__ row_ptr, int* __restrict__ cursor, int m){
  __shared__ int lds[1024];
  int t = threadIdx.x;
  int idx = blockIdx.x * 1024 + t;
  int v = (idx < m) ? rowcnt[idx] : 0;
  lds[t] = v;
  __syncthreads();
#pragma unroll
  for (int o = 1; o < 1024; o <<= 1){
    int u = (t >= o) ? lds[t - o] : 0;
    __syncthreads();
    lds[t] += u;
    __syncthreads();
  }
  if (idx < m){
    int e = lds[t] - v + bscan[blockIdx.x];   // exclusive
    row_ptr[idx] = e;
    cursor[idx]  = e;
  }
}

// ---- bucket-scatter: payload[pos] = src, ordered by key = dst*8+rel ----
__global__ void scatter_build(const int* __restrict__ rel, const int* __restrict__ src,
                              const int* __restrict__ dst, int* __restrict__ cursor,
                              int* __restrict__ payload, int E){
  int stride = gridDim.x * blockDim.x;
  for (int i = blockIdx.x * blockDim.x + threadIdx.x; i < E; i += stride){
    int key = (dst[i] << 3) | rel[i];
    int pos = atomicAdd(&cursor[key], 1);
    payload[pos] = src[i];
  }
}

// ---- fused: per block of 64 nodes, loop r: aggregate (d,r) into LDS tile, MFMA K-chunk ----
// out[d][j] = relu( sum_r sum_k mean_r(x)[d][k] * W[r][j][k] )
__launch_bounds__(256)
__global__ void fused_agg_gemm(const unsigned short* __restrict__ xb,
                               const unsigned short* __restrict__ w2t,
                               const int* __restrict__ row_ptr8,
                               const int* __restrict__ payload,
                               float* __restrict__ out, int n){
  __shared__ __align__(16) unsigned int lds_h[64 * LDW];   // 17.4 KB
  const int wave = threadIdx.x >> 6;
  const int lane = threadIdx.x & 63;
  const int dbase = blockIdx.x * 64;
  const int frow = lane & 15;
  const int kb   = lane >> 4;

  f32x4 acc[8];
#pragma unroll
  for (int jt = 0; jt < 8; ++jt) acc[jt] = (f32x4){0.f, 0.f, 0.f, 0.f};

  for (int r = 0; r < RR; ++r){
    // ---- per-wave: fetch [beg,end) for its 16 nodes in one vector load ----
    int di = dbase + wave * 16 + frow;
    int pv = 0;
    if (lane < 32 && di < n)
      pv = row_ptr8[(di << 3) + r + (lane >> 4)];   // lanes 0-15: beg, 16-31: end

    // ---- aggregate 16 nodes into LDS rows ----
    for (int i = 0; i < 16; ++i){
      int beg = __builtin_amdgcn_readlane(pv, i);
      int end = __builtin_amdgcn_readlane(pv, 16 + i);
      int deg = end - beg;
      float ax = 0.f, ay = 0.f;
      if (deg > 0){
        int pl = payload[beg + lane];               // prefetch up to 64 srcs
        int lim = deg < 64 ? deg : 64;
        for (int e = 0; e < lim; ++e){
          int s = __builtin_amdgcn_readlane(pl, e); // SGPR src id
          unsigned int v = ((const unsigned int*)(xb + (size_t)s * ED))[lane];
          ax += bf2f(v & 0xffffu);
          ay += bf2f(v >> 16);
        }
        for (int e = 64; e < deg; ++e){             // rare tail (deg>64)
          int s = __builtin_amdgcn_readfirstlane(payload[beg + e]);
          unsigned int v = ((const unsigned int*)(xb + (size_t)s * ED))[lane];
          ax += bf2f(v & 0xffffu);
          ay += bf2f(v >> 16);
        }
      }
      float sc = deg > 0 ? 1.f / (float)deg : 0.f;
      lds_h[(wave * 16 + i) * LDW + lane] =
          ((unsigned int)f2bf(ay * sc) << 16) | f2bf(ax * sc);
    }
    __syncthreads();

    // ---- MFMA: wave's 16-row M-tile x 128 cols, K = 128 chunk ----
    short8 a[4];
#pragma unroll
    for (int ks = 0; ks < 4; ++ks)
      a[ks] = *(const short8*)&lds_h[(wave * 16 + frow) * LDW + ks * 16 + kb * 4];
#pragma unroll
    for (int jt = 0; jt < 8; ++jt){
      const unsigned short* wp = w2t + (size_t)(jt * 16 + frow) * KTOT + r * ED + kb * 8;
      short8 b[4];
#pragma unroll
      for (int ks = 0; ks < 4; ++ks)
        b[ks] = *(const short8*)(wp + ks * 32);
#pragma unroll
      for (int ks = 0; ks < 4; ++ks)
        acc[jt] = __builtin_amdgcn_mfma_f32_16x16x32_bf16(a[ks], b[ks], acc[jt], 0, 0, 0);
    }
    __syncthreads();
  }

  // ---- epilogue: D layout col = lane&15, row = (lane>>4)*4 + reg ----
  const int drow = (lane >> 4) * 4;
  const int dcol = lane & 15;
#pragma unroll
  for (int jt = 0; jt < 8; ++jt)
#pragma unroll
    for (int reg = 0; reg < 4; ++reg){
      int i = dbase + wave * 16 + drow + reg;
      if (i < n)
        out[(size_t)i * ED + jt * 16 + dcol] = fmaxf(acc[jt][reg], 0.f);
    }
}

extern "C" void kernel_launch(void* const* d_in, const int* in_sizes, int n_in,
                              void* d_out, int out_size, void* d_ws, size_t ws_size,
                              hipStream_t stream){
  const float* x  = (const float*)d_in[0];
  const float* w  = (const float*)d_in[1];
  const int* erel = (const int*)d_in[2];
  const int* esrc = (const int*)d_in[3];
  const int* edst = (const int*)d_in[4];
  float* out = (float*)d_out;

  const int n = in_sizes[0] / ED;          // 100000
  const int E = in_sizes[2];               // 1600000
  const int m = n * RR;                    // 800000 CSR rows
  const int NB = (m + 1023) / 1024;        // scan blocks (782)

  // ---- workspace layout (256B-aligned segments) ----
  char* ws = (char*)d_ws;
  size_t off = 0;
  auto alloc = [&](size_t bytes) -> char* {
    char* p = ws + off;
    off += (bytes + 255) & ~(size_t)255;
    return p;
  };
  unsigned short* xb      = (unsigned short*)alloc((size_t)n * ED * 2);     // 25.6 MB
  unsigned short* w2t     = (unsigned short*)alloc((size_t)RR * ED * ED * 2);
  int*            payload = (int*)alloc((size_t)E * 4);                     // 6.4 MB
  int*            row_ptr = (int*)alloc((size_t)(m + 1) * 4);               // 3.2 MB (also OOB pad for payload prefetch)
  int*            rowcnt  = (int*)alloc((size_t)m * 4);
  int*            cursor  = (int*)alloc((size_t)m * 4);
  int*            bsum    = (int*)alloc((size_t)NB * 4);
  int*            bscan   = (int*)alloc((size_t)NB * 4);
  if (off > ws_size) return;

  hipMemsetAsync(rowcnt, 0, (size_t)m * 4, stream);

  cast_bf16_vec<<<2048, 256, 0, stream>>>((const float4*)x, (ushort4*)xb, n * ED / 4);
  build_w2t   <<<(RR * ED * ED) / 256, 256, 0, stream>>>(w, w2t);
  hist8       <<<1024, 256, 0, stream>>>(erel, edst, rowcnt, E);
  scan_block_sum<<<NB, 1024, 0, stream>>>(rowcnt, bsum, m);
  scan_bsum   <<<1, 64, 0, stream>>>(bsum, bscan, NB, row_ptr + m);
  scan_final  <<<NB, 1024, 0, stream>>>(rowcnt, bscan, row_ptr, cursor, m);
  scatter_build<<<1024, 256, 0, stream>>>(erel, esrc, edst, cursor, payload, E);
  fused_agg_gemm<<<(n + 63) / 64, 256, 0, stream>>>(xb, w2t, row_ptr, payload, out, n);
}

// Round 4
// 528.712 us; speedup vs baseline: 1.3068x; 1.3068x over previous
//
#include <hip/hip_runtime.h>
#include <hip/hip_bf16.h>

#define ED 128
#define RR 8
#define KTOT (RR * ED)   // 1024

typedef __attribute__((ext_vector_type(8))) short short8;   // 8 x bf16
typedef __attribute__((ext_vector_type(4))) float f32x4;    // MFMA accumulator

__device__ __forceinline__ unsigned short f2bf(float f){
  unsigned int u = __builtin_bit_cast(unsigned int, f);
  return (unsigned short)((u + 0x7fffu + ((u >> 16) & 1u)) >> 16);   // RNE
}
__device__ __forceinline__ float bf2f(unsigned int lo){
  return __builtin_bit_cast(float, lo << 16);
}

// ---- cast f32 -> bf16, 4 at a time ----
__global__ void cast_bf16_vec(const float4* __restrict__ in, ushort4* __restrict__ out, int n4){
  int stride = gridDim.x * blockDim.x;
  for (int i = blockIdx.x * blockDim.x + threadIdx.x; i < n4; i += stride){
    float4 v = in[i];
    ushort4 o;
    o.x = f2bf(v.x); o.y = f2bf(v.y); o.z = f2bf(v.z); o.w = f2bf(v.w);
    out[i] = o;
  }
}

// ---- w2t[j][r*128+kk] = W[r][j][kk]  (B^T layout for the MFMA fragment) ----
__global__ void build_w2t(const float* __restrict__ w, unsigned short* __restrict__ w2t){
  int idx = blockIdx.x * blockDim.x + threadIdx.x;     // over R*ED*ED = 131072
  int kk = idx & 127;
  int j  = (idx >> 7) & 127;
  int r  = idx >> 14;
  w2t[j * KTOT + r * ED + kk] = f2bf(w[idx]);
}

// ---- single atomic pass: histogram + per-edge rank ----
__global__ void hist_rank(const int* __restrict__ rel, const int* __restrict__ dst,
                          int* __restrict__ rowcnt, int* __restrict__ rank, int E){
  int stride = gridDim.x * blockDim.x;
  for (int i = blockIdx.x * blockDim.x + threadIdx.x; i < E; i += stride)
    rank[i] = atomicAdd(&rowcnt[(dst[i] << 3) | rel[i]], 1);
}

// ---- scan step 1: per-block (1024) sums ----
__launch_bounds__(1024)
__global__ void scan_block_sum(const int* __restrict__ rowcnt, int* __restrict__ bsum, int m){
  __shared__ int lds[16];
  int t = threadIdx.x;
  int idx = blockIdx.x * 1024 + t;
  int v = (idx < m) ? rowcnt[idx] : 0;
#pragma unroll
  for (int o = 32; o > 0; o >>= 1) v += __shfl_down(v, o);
  if ((t & 63) == 0) lds[t >> 6] = v;
  __syncthreads();
  if (t == 0){
    int s = 0;
#pragma unroll
    for (int w = 0; w < 16; ++w) s += lds[w];
    bsum[blockIdx.x] = s;
  }
}

// ---- scan step 2: PARALLEL exclusive scan of block sums (nb <= 1024) ----
__launch_bounds__(1024)
__global__ void scan_bsum_par(const int* __restrict__ bsum, int* __restrict__ bscan,
                              int nb, int* __restrict__ total_out){
  __shared__ int wsum[16];
  int t = threadIdx.x, lane = t & 63, wid = t >> 6;
  int v = (t < nb) ? bsum[t] : 0;
  int incl = v;
#pragma unroll
  for (int o = 1; o < 64; o <<= 1){
    int u = __shfl_up(incl, o);
    if (lane >= o) incl += u;
  }
  if (lane == 63) wsum[wid] = incl;
  __syncthreads();
  int woff = 0;
  for (int w0 = 0; w0 < wid; ++w0) woff += wsum[w0];
  if (t < nb) bscan[t] = woff + incl - v;
  if (t == nb - 1) *total_out = woff + incl;     // row_ptr[m] = E
}

// ---- scan step 3: wave-scan + cross-wave offset (1 barrier) ----
__launch_bounds__(1024)
__global__ void scan_final(const int* __restrict__ rowcnt, const int* __restrict__ bscan,
                           int* __restrict__ row_ptr, int m){
  __shared__ int wsum[16];
  int t = threadIdx.x, lane = t & 63, wid = t >> 6;
  int idx = blockIdx.x * 1024 + t;
  int v = (idx < m) ? rowcnt[idx] : 0;
  int incl = v;
#pragma unroll
  for (int o = 1; o < 64; o <<= 1){
    int u = __shfl_up(incl, o);
    if (lane >= o) incl += u;
  }
  if (lane == 63) wsum[wid] = incl;
  __syncthreads();
  int woff = bscan[blockIdx.x];
  for (int w0 = 0; w0 < wid; ++w0) woff += wsum[w0];
  if (idx < m) row_ptr[idx] = woff + incl - v;   // exclusive
}

// ---- atomic-free bucket write: pos = row_ptr[key] + rank ----
__global__ void scatter_pos(const int* __restrict__ rel, const int* __restrict__ src,
                            const int* __restrict__ dst, const int* __restrict__ rank,
                            const int* __restrict__ row_ptr, int* __restrict__ payload, int E){
  int stride = gridDim.x * blockDim.x;
  for (int i = blockIdx.x * blockDim.x + threadIdx.x; i < E; i += stride){
    int key = (dst[i] << 3) | rel[i];
    payload[row_ptr[key] + rank[i]] = src[i];
  }
}

// ---- one wave per node: h2[d][r*128+k] = mean over segment (d,r); no switch, no atomics ----
__launch_bounds__(256)
__global__ void row_agg(const unsigned short* __restrict__ xb,
                        const int* __restrict__ row_ptr8,
                        const int* __restrict__ payload,
                        unsigned short* __restrict__ h2, int n){
  int d = (blockIdx.x * 256 + threadIdx.x) >> 6;
  int lane = threadIdx.x & 63;
  if (d >= n) return;
  int p9 = 0;
  if (lane < 9) p9 = row_ptr8[(d << 3) + lane];     // 9 segment boundaries
  int base = __builtin_amdgcn_readlane(p9, 0);
  int pl = payload[base + lane];                    // window 0 prefetch (<= 64 edges)
  int win = 0;
  unsigned int* hp = (unsigned int*)h2 + ((size_t)d << 9) + lane;
#pragma unroll
  for (int r = 0; r < RR; ++r){
    int beg = __builtin_amdgcn_readlane(p9, r);
    int end = __builtin_amdgcn_readlane(p9, r + 1);
    float ax = 0.f, ay = 0.f;
    for (int e = beg; e < end; ++e){
      int idx = e - base;
      if ((idx >> 6) != win){                       // rare: node with >64 total edges
        win = idx >> 6;
        pl = payload[base + (win << 6) + lane];
      }
      int s = __builtin_amdgcn_readlane(pl, idx & 63);     // SGPR src id
      unsigned int v = ((const unsigned int*)(xb + ((size_t)s << 7)))[lane];  // 256B coalesced
      ax += bf2f(v & 0xffffu);
      ay += bf2f(v >> 16);
    }
    float sc = (end > beg) ? 1.f / (float)(end - beg) : 0.f;
    hp[r << 6] = ((unsigned int)f2bf(ay * sc) << 16) | f2bf(ax * sc);
  }
}

// ---- out[d][j] = relu( sum_k h2[d][k] * w2t[j][k] ), K=1024; LDS-staged A ----
__launch_bounds__(256)
__global__ void gemm_out(const unsigned short* __restrict__ h2,
                         const unsigned short* __restrict__ w2t,
                         float* __restrict__ out, int n){
  __shared__ __align__(16) unsigned int lds_a[64 * 68];   // 64 rows x 128 bf16, +4dw pad
  const int t = threadIdx.x;
  const int wave = t >> 6, lane = t & 63;
  const int dbase = blockIdx.x * 64;
  const int frow = lane & 15, kb = lane >> 4;

  f32x4 acc[8];
#pragma unroll
  for (int jt = 0; jt < 8; ++jt) acc[jt] = (f32x4){0.f, 0.f, 0.f, 0.f};

  for (int kc = 0; kc < 8; ++kc){
    __syncthreads();
    // stage A chunk: 64 rows x 256B, coalesced (16 threads x 16B per row)
#pragma unroll
    for (int p = 0; p < 4; ++p){
      int q = p * 256 + t;
      int row = q >> 4, col = q & 15;
      short8 vv = *(const short8*)(h2 + (size_t)(dbase + row) * KTOT + kc * 128 + col * 8);
      *(short8*)&lds_a[row * 68 + col * 4] = vv;
    }
    __syncthreads();

    short8 a[4];
#pragma unroll
    for (int ks = 0; ks < 4; ++ks)
      a[ks] = *(const short8*)&lds_a[(wave * 16 + frow) * 68 + ks * 16 + kb * 4];
#pragma unroll
    for (int jt = 0; jt < 8; ++jt){
      const unsigned short* wp = w2t + (size_t)(jt * 16 + frow) * KTOT + kc * 128 + kb * 8;
      short8 b[4];
#pragma unroll
      for (int ks = 0; ks < 4; ++ks)
        b[ks] = *(const short8*)(wp + ks * 32);
#pragma unroll
      for (int ks = 0; ks < 4; ++ks)
        acc[jt] = __builtin_amdgcn_mfma_f32_16x16x32_bf16(a[ks], b[ks], acc[jt], 0, 0, 0);
    }
  }

  // D layout: col = lane&15, row = (lane>>4)*4 + reg
  const int drow = (lane >> 4) * 4;
  const int dcol = lane & 15;
#pragma unroll
  for (int jt = 0; jt < 8; ++jt)
#pragma unroll
    for (int reg = 0; reg < 4; ++reg){
      int i = dbase + wave * 16 + drow + reg;
      if (i < n)
        out[(size_t)i * ED + jt * 16 + dcol] = fmaxf(acc[jt][reg], 0.f);
    }
}

extern "C" void kernel_launch(void* const* d_in, const int* in_sizes, int n_in,
                              void* d_out, int out_size, void* d_ws, size_t ws_size,
                              hipStream_t stream){
  const float* x  = (const float*)d_in[0];
  const float* w  = (const float*)d_in[1];
  const int* erel = (const int*)d_in[2];
  const int* esrc = (const int*)d_in[3];
  const int* edst = (const int*)d_in[4];
  float* out = (float*)d_out;

  const int n = in_sizes[0] / ED;          // 100000
  const int E = in_sizes[2];               // 1600000
  const int m = n * RR;                    // 800000 CSR rows
  const int NB = (m + 1023) / 1024;        // 782 (must be <= 1024)

  // ---- workspace layout (256B-aligned segments) ----
  char* ws = (char*)d_ws;
  size_t off = 0;
  auto alloc = [&](size_t bytes) -> char* {
    char* p = ws + off;
    off += (bytes + 255) & ~(size_t)255;
    return p;
  };
  unsigned short* h2      = (unsigned short*)alloc((size_t)n * KTOT * 2);   // 204.8 MB
  unsigned short* xb      = (unsigned short*)alloc((size_t)n * ED * 2);     // 25.6 MB
  unsigned short* w2t     = (unsigned short*)alloc((size_t)RR * ED * ED * 2);
  int*            payload = (int*)alloc((size_t)E * 4);                     // 6.4 MB
  int*            row_ptr = (int*)alloc((size_t)(m + 1) * 4);               // 3.2 MB (pads payload OOB prefetch)
  int*            rowcnt  = (int*)alloc((size_t)m * 4);
  int*            rank    = (int*)alloc((size_t)E * 4);                     // 6.4 MB
  int*            bsum    = (int*)alloc((size_t)NB * 4);
  int*            bscan   = (int*)alloc((size_t)NB * 4);
  if (off > ws_size || NB > 1024) return;

  hipMemsetAsync(rowcnt, 0, (size_t)m * 4, stream);

  cast_bf16_vec<<<2048, 256, 0, stream>>>((const float4*)x, (ushort4*)xb, n * ED / 4);
  build_w2t    <<<(RR * ED * ED) / 256, 256, 0, stream>>>(w, w2t);
  hist_rank    <<<2048, 256, 0, stream>>>(erel, edst, rowcnt, rank, E);
  scan_block_sum<<<NB, 1024, 0, stream>>>(rowcnt, bsum, m);
  scan_bsum_par<<<1, 1024, 0, stream>>>(bsum, bscan, NB, row_ptr + m);
  scan_final   <<<NB, 1024, 0, stream>>>(rowcnt, bscan, row_ptr, m);
  scatter_pos  <<<2048, 256, 0, stream>>>(erel, esrc, edst, rank, row_ptr, payload, E);
  row_agg      <<<(n + 3) / 4, 256, 0, stream>>>(xb, row_ptr, payload, h2, n);
  gemm_out     <<<(n + 63) / 64, 256, 0, stream>>>(h2, w2t, out, n);
}

// Round 5
// 336.064 us; speedup vs baseline: 2.0559x; 1.5732x over previous
//
#include <hip/hip_runtime.h>
#include <hip/hip_bf16.h>

#define ED 128
#define RR 8
#define KTOT (RR * ED)   // 1024
#define LDB 136          // LDS row stride in shorts (128 data + 8 pad) -> 68 dwords, 2-way free

typedef __attribute__((ext_vector_type(8))) short short8;   // 8 x bf16
typedef __attribute__((ext_vector_type(4))) float f32x4;    // MFMA accumulator

__device__ __forceinline__ unsigned short f2bf(float f){
  unsigned int u = __builtin_bit_cast(unsigned int, f);
  return (unsigned short)((u + 0x7fffu + ((u >> 16) & 1u)) >> 16);   // RNE
}
__device__ __forceinline__ float bf2f(unsigned int lo){
  return __builtin_bit_cast(float, lo << 16);
}

// ---- cast f32 -> bf16, 4 at a time ----
__global__ void cast_bf16_vec(const float4* __restrict__ in, ushort4* __restrict__ out, int n4){
  int stride = gridDim.x * blockDim.x;
  for (int i = blockIdx.x * blockDim.x + threadIdx.x; i < n4; i += stride){
    float4 v = in[i];
    ushort4 o;
    o.x = f2bf(v.x); o.y = f2bf(v.y); o.z = f2bf(v.z); o.w = f2bf(v.w);
    out[i] = o;
  }
}

// ---- single atomic pass: histogram + per-edge rank ----
__global__ void hist_rank(const int* __restrict__ rel, const int* __restrict__ dst,
                          int* __restrict__ rowcnt, int* __restrict__ rank, int E){
  int stride = gridDim.x * blockDim.x;
  for (int i = blockIdx.x * blockDim.x + threadIdx.x; i < E; i += stride)
    rank[i] = atomicAdd(&rowcnt[(dst[i] << 3) | rel[i]], 1);
}

// ---- scan step 1: per-block (1024) sums ----
__launch_bounds__(1024)
__global__ void scan_block_sum(const int* __restrict__ rowcnt, int* __restrict__ bsum, int m){
  __shared__ int lds[16];
  int t = threadIdx.x;
  int idx = blockIdx.x * 1024 + t;
  int v = (idx < m) ? rowcnt[idx] : 0;
#pragma unroll
  for (int o = 32; o > 0; o >>= 1) v += __shfl_down(v, o);
  if ((t & 63) == 0) lds[t >> 6] = v;
  __syncthreads();
  if (t == 0){
    int s = 0;
#pragma unroll
    for (int w = 0; w < 16; ++w) s += lds[w];
    bsum[blockIdx.x] = s;
  }
}

// ---- scan step 2: PARALLEL exclusive scan of block sums (nb <= 1024) ----
__launch_bounds__(1024)
__global__ void scan_bsum_par(const int* __restrict__ bsum, int* __restrict__ bscan,
                              int nb, int* __restrict__ total_out){
  __shared__ int wsum[16];
  int t = threadIdx.x, lane = t & 63, wid = t >> 6;
  int v = (t < nb) ? bsum[t] : 0;
  int incl = v;
#pragma unroll
  for (int o = 1; o < 64; o <<= 1){
    int u = __shfl_up(incl, o);
    if (lane >= o) incl += u;
  }
  if (lane == 63) wsum[wid] = incl;
  __syncthreads();
  int woff = 0;
  for (int w0 = 0; w0 < wid; ++w0) woff += wsum[w0];
  if (t < nb) bscan[t] = woff + incl - v;
  if (t == nb - 1) *total_out = woff + incl;     // row_ptr[m] = E
}

// ---- scan step 3: wave-scan + cross-wave offset (1 barrier) ----
__launch_bounds__(1024)
__global__ void scan_final(const int* __restrict__ rowcnt, const int* __restrict__ bscan,
                           int* __restrict__ row_ptr, int m){
  __shared__ int wsum[16];
  int t = threadIdx.x, lane = t & 63, wid = t >> 6;
  int idx = blockIdx.x * 1024 + t;
  int v = (idx < m) ? rowcnt[idx] : 0;
  int incl = v;
#pragma unroll
  for (int o = 1; o < 64; o <<= 1){
    int u = __shfl_up(incl, o);
    if (lane >= o) incl += u;
  }
  if (lane == 63) wsum[wid] = incl;
  __syncthreads();
  int woff = bscan[blockIdx.x];
  for (int w0 = 0; w0 < wid; ++w0) woff += wsum[w0];
  if (idx < m) row_ptr[idx] = woff + incl - v;   // exclusive
}

// ---- atomic-free bucket write: pos = row_ptr[key] + rank ----
__global__ void scatter_pos(const int* __restrict__ rel, const int* __restrict__ src,
                            const int* __restrict__ dst, const int* __restrict__ rank,
                            const int* __restrict__ row_ptr, int* __restrict__ payload, int E){
  int stride = gridDim.x * blockDim.x;
  for (int i = blockIdx.x * blockDim.x + threadIdx.x; i < E; i += stride){
    int key = (dst[i] << 3) | rel[i];
    payload[row_ptr[key] + rank[i]] = src[i];
  }
}

// ---- one wave per node: h2[d][r*128+k] = mean over segment (d,r); no switch, no atomics ----
__launch_bounds__(256)
__global__ void row_agg(const unsigned short* __restrict__ xb,
                        const int* __restrict__ row_ptr8,
                        const int* __restrict__ payload,
                        unsigned short* __restrict__ h2, int n){
  int d = (blockIdx.x * 256 + threadIdx.x) >> 6;
  int lane = threadIdx.x & 63;
  if (d >= n) return;
  int p9 = 0;
  if (lane < 9) p9 = row_ptr8[(d << 3) + lane];     // 9 segment boundaries
  int base = __builtin_amdgcn_readlane(p9, 0);
  int pl = payload[base + lane];                    // window 0 prefetch (<= 64 edges)
  int win = 0;
  unsigned int* hp = (unsigned int*)h2 + ((size_t)d << 9) + lane;
#pragma unroll
  for (int r = 0; r < RR; ++r){
    int beg = __builtin_amdgcn_readlane(p9, r);
    int end = __builtin_amdgcn_readlane(p9, r + 1);
    float ax = 0.f, ay = 0.f;
    for (int e = beg; e < end; ++e){
      int idx = e - base;
      if ((idx >> 6) != win){                       // rare: node with >64 total edges
        win = idx >> 6;
        pl = payload[base + (win << 6) + lane];
      }
      int s = __builtin_amdgcn_readlane(pl, idx & 63);     // SGPR src id
      unsigned int v = ((const unsigned int*)(xb + ((size_t)s << 7)))[lane];  // 256B coalesced
      ax += bf2f(v & 0xffffu);
      ay += bf2f(v >> 16);
    }
    float sc = (end > beg) ? 1.f / (float)(end - beg) : 0.f;
    hp[r << 6] = ((unsigned int)f2bf(ay * sc) << 16) | f2bf(ax * sc);
  }
}

// ---- out[d][j] = relu( sum_r sum_kk h2[d][r*128+kk] * W[r][j][kk] ) ----
// 128x128 block tile, 4 waves in 2x2 grid (each 64 rows x 64 cols), A+B LDS-staged per r
__launch_bounds__(256)
__global__ void gemm_out(const unsigned short* __restrict__ h2,
                         const unsigned short* __restrict__ wbb,
                         float* __restrict__ out, int n){
  __shared__ __align__(16) unsigned short lds_a[128 * LDB];   // 34.8 KB
  __shared__ __align__(16) unsigned short lds_b[128 * LDB];   // 34.8 KB
  const int t = threadIdx.x;
  const int wave = t >> 6, lane = t & 63;
  const int wr = wave >> 1, wc = wave & 1;        // 2x2 wave grid
  const int dbase = blockIdx.x * 128;
  const int frow = lane & 15, kb = lane >> 4;

  f32x4 acc[4][4];
#pragma unroll
  for (int rt = 0; rt < 4; ++rt)
#pragma unroll
    for (int jt = 0; jt < 4; ++jt)
      acc[rt][jt] = (f32x4){0.f, 0.f, 0.f, 0.f};

  for (int r = 0; r < RR; ++r){
    __syncthreads();                               // protect LDS from prev-iter readers
    // stage A chunk: 128 rows x 256B (row-clamped at the M-tail)
#pragma unroll
    for (int p = 0; p < 8; ++p){
      int q = p * 256 + t;
      int row = q >> 4, col = q & 15;
      int gr = dbase + row; if (gr >= n) gr = n - 1;
      *(short8*)&lds_a[row * LDB + col * 8] =
          *(const short8*)(h2 + (size_t)gr * KTOT + r * ED + col * 8);
    }
    // stage B chunk: W[r], 32 KB fully contiguous
    const unsigned short* wp = wbb + (size_t)r * ED * ED;
#pragma unroll
    for (int p = 0; p < 8; ++p){
      int q = p * 256 + t;
      int row = q >> 4, col = q & 15;
      *(short8*)&lds_b[row * LDB + col * 8] = *(const short8*)(wp + row * ED + col * 8);
    }
    __syncthreads();

    short8 a[4][4], b[4][4];
#pragma unroll
    for (int rt = 0; rt < 4; ++rt)
#pragma unroll
      for (int ks = 0; ks < 4; ++ks)
        a[rt][ks] = *(const short8*)&lds_a[(wr * 64 + rt * 16 + frow) * LDB + ks * 32 + kb * 8];
#pragma unroll
    for (int jt = 0; jt < 4; ++jt)
#pragma unroll
      for (int ks = 0; ks < 4; ++ks)
        b[jt][ks] = *(const short8*)&lds_b[(wc * 64 + jt * 16 + frow) * LDB + ks * 32 + kb * 8];
#pragma unroll
    for (int rt = 0; rt < 4; ++rt)
#pragma unroll
      for (int jt = 0; jt < 4; ++jt)
#pragma unroll
        for (int ks = 0; ks < 4; ++ks)
          acc[rt][jt] = __builtin_amdgcn_mfma_f32_16x16x32_bf16(a[rt][ks], b[jt][ks], acc[rt][jt], 0, 0, 0);
  }

  // D layout: col = lane&15, row = (lane>>4)*4 + reg
  const int drow = (lane >> 4) * 4;
  const int dcol = lane & 15;
#pragma unroll
  for (int rt = 0; rt < 4; ++rt)
#pragma unroll
    for (int jt = 0; jt < 4; ++jt)
#pragma unroll
      for (int reg = 0; reg < 4; ++reg){
        int i = dbase + wr * 64 + rt * 16 + drow + reg;
        if (i < n)
          out[(size_t)i * ED + wc * 64 + jt * 16 + dcol] = fmaxf(acc[rt][jt][reg], 0.f);
      }
}

extern "C" void kernel_launch(void* const* d_in, const int* in_sizes, int n_in,
                              void* d_out, int out_size, void* d_ws, size_t ws_size,
                              hipStream_t stream){
  const float* x  = (const float*)d_in[0];
  const float* w  = (const float*)d_in[1];
  const int* erel = (const int*)d_in[2];
  const int* esrc = (const int*)d_in[3];
  const int* edst = (const int*)d_in[4];
  float* out = (float*)d_out;

  const int n = in_sizes[0] / ED;          // 100000
  const int E = in_sizes[2];               // 1600000
  const int m = n * RR;                    // 800000 CSR rows
  const int NB = (m + 1023) / 1024;        // 782 (must be <= 1024)

  // ---- workspace layout (256B-aligned segments) ----
  char* ws = (char*)d_ws;
  size_t off = 0;
  auto alloc = [&](size_t bytes) -> char* {
    char* p = ws + off;
    off += (bytes + 255) & ~(size_t)255;
    return p;
  };
  unsigned short* h2      = (unsigned short*)alloc((size_t)n * KTOT * 2);   // 204.8 MB
  unsigned short* xb      = (unsigned short*)alloc((size_t)n * ED * 2);     // 25.6 MB
  unsigned short* wbb     = (unsigned short*)alloc((size_t)RR * ED * ED * 2); // 256 KB
  int*            payload = (int*)alloc((size_t)E * 4);                     // 6.4 MB
  int*            row_ptr = (int*)alloc((size_t)(m + 1) * 4);               // 3.2 MB (pads payload OOB prefetch)
  int*            rowcnt  = (int*)alloc((size_t)m * 4);
  int*            rank    = (int*)alloc((size_t)E * 4);                     // 6.4 MB
  int*            bsum    = (int*)alloc((size_t)NB * 4);
  int*            bscan   = (int*)alloc((size_t)NB * 4);
  if (off > ws_size || NB > 1024) return;

  hipMemsetAsync(rowcnt, 0, (size_t)m * 4, stream);

  cast_bf16_vec<<<2048, 256, 0, stream>>>((const float4*)x, (ushort4*)xb, n * ED / 4);
  cast_bf16_vec<<<128, 256, 0, stream>>>((const float4*)w, (ushort4*)wbb, RR * ED * ED / 4);
  hist_rank    <<<2048, 256, 0, stream>>>(erel, edst, rowcnt, rank, E);
  scan_block_sum<<<NB, 1024, 0, stream>>>(rowcnt, bsum, m);
  scan_bsum_par<<<1, 1024, 0, stream>>>(bsum, bscan, NB, row_ptr + m);
  scan_final   <<<NB, 1024, 0, stream>>>(rowcnt, bscan, row_ptr, m);
  scatter_pos  <<<2048, 256, 0, stream>>>(erel, esrc, edst, rank, row_ptr, payload, E);
  row_agg      <<<(n + 3) / 4, 256, 0, stream>>>(xb, row_ptr, payload, h2, n);
  gemm_out     <<<(n + 127) / 128, 256, 0, stream>>>(h2, wbb, out, n);
}

// Round 6
// 319.163 us; speedup vs baseline: 2.1648x; 1.0530x over previous
//
#include <hip/hip_runtime.h>
#include <hip/hip_bf16.h>

#define ED 128
#define RR 8
#define KTOT (RR * ED)   // 1024
#define LDB 136          // LDS row stride in shorts (128 data + 8 pad) -> 68 dwords, 2-way free

typedef __attribute__((ext_vector_type(8))) short short8;   // 8 x bf16
typedef __attribute__((ext_vector_type(4))) float f32x4;    // MFMA accumulator

__device__ __forceinline__ unsigned short f2bf(float f){
  unsigned int u = __builtin_bit_cast(unsigned int, f);
  return (unsigned short)((u + 0x7fffu + ((u >> 16) & 1u)) >> 16);   // RNE
}
__device__ __forceinline__ float bf2f(unsigned int lo){
  return __builtin_bit_cast(float, lo << 16);
}

// ---- cast f32 -> bf16, 4 at a time ----
__global__ void cast_bf16_vec(const float4* __restrict__ in, ushort4* __restrict__ out, int n4){
  int stride = gridDim.x * blockDim.x;
  for (int i = blockIdx.x * blockDim.x + threadIdx.x; i < n4; i += stride){
    float4 v = in[i];
    ushort4 o;
    o.x = f2bf(v.x); o.y = f2bf(v.y); o.z = f2bf(v.z); o.w = f2bf(v.w);
    out[i] = o;
  }
}

// ---- single atomic pass: histogram + per-edge rank ----
__global__ void hist_rank(const int* __restrict__ rel, const int* __restrict__ dst,
                          int* __restrict__ rowcnt, int* __restrict__ rank, int E){
  int stride = gridDim.x * blockDim.x;
  for (int i = blockIdx.x * blockDim.x + threadIdx.x; i < E; i += stride)
    rank[i] = atomicAdd(&rowcnt[(dst[i] << 3) | rel[i]], 1);
}

// ---- scan step 1: per-block (1024) sums ----
__launch_bounds__(1024)
__global__ void scan_block_sum(const int* __restrict__ rowcnt, int* __restrict__ bsum, int m){
  __shared__ int lds[16];
  int t = threadIdx.x;
  int idx = blockIdx.x * 1024 + t;
  int v = (idx < m) ? rowcnt[idx] : 0;
#pragma unroll
  for (int o = 32; o > 0; o >>= 1) v += __shfl_down(v, o);
  if ((t & 63) == 0) lds[t >> 6] = v;
  __syncthreads();
  if (t == 0){
    int s = 0;
#pragma unroll
    for (int w = 0; w < 16; ++w) s += lds[w];
    bsum[blockIdx.x] = s;
  }
}

// ---- scan step 2: PARALLEL exclusive scan of block sums (nb <= 1024) ----
__launch_bounds__(1024)
__global__ void scan_bsum_par(const int* __restrict__ bsum, int* __restrict__ bscan,
                              int nb, int* __restrict__ total_out){
  __shared__ int wsum[16];
  int t = threadIdx.x, lane = t & 63, wid = t >> 6;
  int v = (t < nb) ? bsum[t] : 0;
  int incl = v;
#pragma unroll
  for (int o = 1; o < 64; o <<= 1){
    int u = __shfl_up(incl, o);
    if (lane >= o) incl += u;
  }
  if (lane == 63) wsum[wid] = incl;
  __syncthreads();
  int woff = 0;
  for (int w0 = 0; w0 < wid; ++w0) woff += wsum[w0];
  if (t < nb) bscan[t] = woff + incl - v;
  if (t == nb - 1) *total_out = woff + incl;     // row_ptr[m] = E
}

// ---- scan step 3: wave-scan + cross-wave offset (1 barrier) ----
__launch_bounds__(1024)
__global__ void scan_final(const int* __restrict__ rowcnt, const int* __restrict__ bscan,
                           int* __restrict__ row_ptr, int m){
  __shared__ int wsum[16];
  int t = threadIdx.x, lane = t & 63, wid = t >> 6;
  int idx = blockIdx.x * 1024 + t;
  int v = (idx < m) ? rowcnt[idx] : 0;
  int incl = v;
#pragma unroll
  for (int o = 1; o < 64; o <<= 1){
    int u = __shfl_up(incl, o);
    if (lane >= o) incl += u;
  }
  if (lane == 63) wsum[wid] = incl;
  __syncthreads();
  int woff = bscan[blockIdx.x];
  for (int w0 = 0; w0 < wid; ++w0) woff += wsum[w0];
  if (idx < m) row_ptr[idx] = woff + incl - v;   // exclusive
}

// ---- atomic-free bucket write: pos = row_ptr[key] + rank ----
__global__ void scatter_pos(const int* __restrict__ rel, const int* __restrict__ src,
                            const int* __restrict__ dst, const int* __restrict__ rank,
                            const int* __restrict__ row_ptr, int* __restrict__ payload, int E){
  int stride = gridDim.x * blockDim.x;
  for (int i = blockIdx.x * blockDim.x + threadIdx.x; i < E; i += stride){
    int key = (dst[i] << 3) | rel[i];
    payload[row_ptr[key] + rank[i]] = src[i];
  }
}

// ---- 4 waves per node (2 relations each): batched 4-deep gathers for MLP ----
__launch_bounds__(256)
__global__ void row_agg(const unsigned short* __restrict__ xb,
                        const int* __restrict__ row_ptr8,
                        const int* __restrict__ payload,
                        unsigned short* __restrict__ h2, int n){
  int wv   = (blockIdx.x * 256 + threadIdx.x) >> 6;
  int lane = threadIdx.x & 63;
  int d    = wv >> 2;
  int half = wv & 3;                               // relations 2*half, 2*half+1
  if (d >= n) return;

  int p3 = 0;
  if (lane < 3) p3 = row_ptr8[(d << 3) + (half << 1) + lane];
  int b0 = __builtin_amdgcn_readlane(p3, 0);
  int b1 = __builtin_amdgcn_readlane(p3, 1);
  int b2 = __builtin_amdgcn_readlane(p3, 2);
  unsigned int* hp = (unsigned int*)h2 + ((size_t)d << 9) + ((size_t)half << 7) + lane;

  if (b2 - b0 <= 64){                              // fast path: one payload window
    int pl = payload[b0 + lane];                   // (reads past E land in row_ptr pad)
#pragma unroll
    for (int rr = 0; rr < 2; ++rr){
      int beg = rr ? b1 : b0;
      int end = rr ? b2 : b1;
      float ax = 0.f, ay = 0.f;
      for (int e = beg; e < end; e += 4){
        // clamp slot indices (uniform scalars); issue all loads before any use
        int i0 = e - b0;
        int i1 = (e + 1 < end ? e + 1 : end - 1) - b0;
        int i2 = (e + 2 < end ? e + 2 : end - 1) - b0;
        int i3 = (e + 3 < end ? e + 3 : end - 1) - b0;
        unsigned int v0 = 0, v1 = 0, v2 = 0, v3 = 0;
        int s0 = __builtin_amdgcn_readlane(pl, i0);
        v0 = ((const unsigned int*)(xb + ((size_t)s0 << 7)))[lane];
        if (e + 1 < end){
          int s1 = __builtin_amdgcn_readlane(pl, i1);
          v1 = ((const unsigned int*)(xb + ((size_t)s1 << 7)))[lane];
        }
        if (e + 2 < end){
          int s2 = __builtin_amdgcn_readlane(pl, i2);
          v2 = ((const unsigned int*)(xb + ((size_t)s2 << 7)))[lane];
        }
        if (e + 3 < end){
          int s3 = __builtin_amdgcn_readlane(pl, i3);
          v3 = ((const unsigned int*)(xb + ((size_t)s3 << 7)))[lane];
        }
        ax += bf2f(v0 & 0xffffu); ay += bf2f(v0 >> 16);
        ax += bf2f(v1 & 0xffffu); ay += bf2f(v1 >> 16);
        ax += bf2f(v2 & 0xffffu); ay += bf2f(v2 >> 16);
        ax += bf2f(v3 & 0xffffu); ay += bf2f(v3 >> 16);
      }
      float sc = (end > beg) ? 1.f / (float)(end - beg) : 0.f;
      hp[rr << 6] = ((unsigned int)f2bf(ay * sc) << 16) | f2bf(ax * sc);
    }
  } else {                                         // rare fat node: serial path
#pragma unroll
    for (int rr = 0; rr < 2; ++rr){
      int beg = rr ? b1 : b0;
      int end = rr ? b2 : b1;
      float ax = 0.f, ay = 0.f;
      for (int e = beg; e < end; ++e){
        int s = __builtin_amdgcn_readfirstlane(payload[e]);
        unsigned int v = ((const unsigned int*)(xb + ((size_t)s << 7)))[lane];
        ax += bf2f(v & 0xffffu);
        ay += bf2f(v >> 16);
      }
      float sc = (end > beg) ? 1.f / (float)(end - beg) : 0.f;
      hp[rr << 6] = ((unsigned int)f2bf(ay * sc) << 16) | f2bf(ax * sc);
    }
  }
}

// ---- out[d][j] = relu( sum_r sum_kk h2[d][r*128+kk] * W[r][j][kk] ) ----
// 128x128 block tile, 4 waves in 2x2 grid (each 64 rows x 64 cols), A+B LDS-staged per r
__launch_bounds__(256)
__global__ void gemm_out(const unsigned short* __restrict__ h2,
                         const unsigned short* __restrict__ wbb,
                         float* __restrict__ out, int n){
  __shared__ __align__(16) unsigned short lds_a[128 * LDB];   // 34.8 KB
  __shared__ __align__(16) unsigned short lds_b[128 * LDB];   // 34.8 KB
  const int t = threadIdx.x;
  const int wave = t >> 6, lane = t & 63;
  const int wr = wave >> 1, wc = wave & 1;        // 2x2 wave grid
  const int dbase = blockIdx.x * 128;
  const int frow = lane & 15, kb = lane >> 4;

  f32x4 acc[4][4];
#pragma unroll
  for (int rt = 0; rt < 4; ++rt)
#pragma unroll
    for (int jt = 0; jt < 4; ++jt)
      acc[rt][jt] = (f32x4){0.f, 0.f, 0.f, 0.f};

  for (int r = 0; r < RR; ++r){
    __syncthreads();                               // protect LDS from prev-iter readers
    // stage A chunk: 128 rows x 256B (row-clamped at the M-tail)
#pragma unroll
    for (int p = 0; p < 8; ++p){
      int q = p * 256 + t;
      int row = q >> 4, col = q & 15;
      int gr = dbase + row; if (gr >= n) gr = n - 1;
      *(short8*)&lds_a[row * LDB + col * 8] =
          *(const short8*)(h2 + (size_t)gr * KTOT + r * ED + col * 8);
    }
    // stage B chunk: W[r], 32 KB fully contiguous
    const unsigned short* wp = wbb + (size_t)r * ED * ED;
#pragma unroll
    for (int p = 0; p < 8; ++p){
      int q = p * 256 + t;
      int row = q >> 4, col = q & 15;
      *(short8*)&lds_b[row * LDB + col * 8] = *(const short8*)(wp + row * ED + col * 8);
    }
    __syncthreads();

    short8 a[4][4], b[4][4];
#pragma unroll
    for (int rt = 0; rt < 4; ++rt)
#pragma unroll
      for (int ks = 0; ks < 4; ++ks)
        a[rt][ks] = *(const short8*)&lds_a[(wr * 64 + rt * 16 + frow) * LDB + ks * 32 + kb * 8];
#pragma unroll
    for (int jt = 0; jt < 4; ++jt)
#pragma unroll
      for (int ks = 0; ks < 4; ++ks)
        b[jt][ks] = *(const short8*)&lds_b[(wc * 64 + jt * 16 + frow) * LDB + ks * 32 + kb * 8];
#pragma unroll
    for (int rt = 0; rt < 4; ++rt)
#pragma unroll
      for (int jt = 0; jt < 4; ++jt)
#pragma unroll
        for (int ks = 0; ks < 4; ++ks)
          acc[rt][jt] = __builtin_amdgcn_mfma_f32_16x16x32_bf16(a[rt][ks], b[jt][ks], acc[rt][jt], 0, 0, 0);
  }

  // D layout: col = lane&15, row = (lane>>4)*4 + reg
  const int drow = (lane >> 4) * 4;
  const int dcol = lane & 15;
#pragma unroll
  for (int rt = 0; rt < 4; ++rt)
#pragma unroll
    for (int jt = 0; jt < 4; ++jt)
#pragma unroll
      for (int reg = 0; reg < 4; ++reg){
        int i = dbase + wr * 64 + rt * 16 + drow + reg;
        if (i < n)
          out[(size_t)i * ED + wc * 64 + jt * 16 + dcol] = fmaxf(acc[rt][jt][reg], 0.f);
      }
}

extern "C" void kernel_launch(void* const* d_in, const int* in_sizes, int n_in,
                              void* d_out, int out_size, void* d_ws, size_t ws_size,
                              hipStream_t stream){
  const float* x  = (const float*)d_in[0];
  const float* w  = (const float*)d_in[1];
  const int* erel = (const int*)d_in[2];
  const int* esrc = (const int*)d_in[3];
  const int* edst = (const int*)d_in[4];
  float* out = (float*)d_out;

  const int n = in_sizes[0] / ED;          // 100000
  const int E = in_sizes[2];               // 1600000
  const int m = n * RR;                    // 800000 CSR rows
  const int NB = (m + 1023) / 1024;        // 782 (must be <= 1024)

  // ---- workspace layout (256B-aligned segments) ----
  char* ws = (char*)d_ws;
  size_t off = 0;
  auto alloc = [&](size_t bytes) -> char* {
    char* p = ws + off;
    off += (bytes + 255) & ~(size_t)255;
    return p;
  };
  unsigned short* h2      = (unsigned short*)alloc((size_t)n * KTOT * 2);   // 204.8 MB
  unsigned short* xb      = (unsigned short*)alloc((size_t)n * ED * 2);     // 25.6 MB
  unsigned short* wbb     = (unsigned short*)alloc((size_t)RR * ED * ED * 2); // 256 KB
  int*            payload = (int*)alloc((size_t)E * 4);                     // 6.4 MB
  int*            row_ptr = (int*)alloc((size_t)(m + 1) * 4);               // 3.2 MB (pads payload OOB prefetch)
  int*            rowcnt  = (int*)alloc((size_t)m * 4);
  int*            rank    = (int*)alloc((size_t)E * 4);                     // 6.4 MB
  int*            bsum    = (int*)alloc((size_t)NB * 4);
  int*            bscan   = (int*)alloc((size_t)NB * 4);
  if (off > ws_size || NB > 1024) return;

  hipMemsetAsync(rowcnt, 0, (size_t)m * 4, stream);

  cast_bf16_vec<<<2048, 256, 0, stream>>>((const float4*)x, (ushort4*)xb, n * ED / 4);
  cast_bf16_vec<<<128, 256, 0, stream>>>((const float4*)w, (ushort4*)wbb, RR * ED * ED / 4);
  hist_rank    <<<2048, 256, 0, stream>>>(erel, edst, rowcnt, rank, E);
  scan_block_sum<<<NB, 1024, 0, stream>>>(rowcnt, bsum, m);
  scan_bsum_par<<<1, 1024, 0, stream>>>(bsum, bscan, NB, row_ptr + m);
  scan_final   <<<NB, 1024, 0, stream>>>(rowcnt, bscan, row_ptr, m);
  scatter_pos  <<<2048, 256, 0, stream>>>(erel, esrc, edst, rank, row_ptr, payload, E);
  row_agg      <<<(n * 4 + 3) / 4, 256, 0, stream>>>(xb, row_ptr, payload, h2, n);
  gemm_out     <<<(n + 127) / 128, 256, 0, stream>>>(h2, wbb, out, n);
}

// Round 8
// 293.048 us; speedup vs baseline: 2.3577x; 1.0891x over previous
//
#include <hip/hip_runtime.h>
#include <hip/hip_bf16.h>

#define ED 128
#define RR 8
#define KTOT (RR * ED)   // 1024
#define LDB 136          // LDS row stride in shorts (128 data + 8 pad) -> 68 dwords, 2-way free

typedef __attribute__((ext_vector_type(8))) short short8;   // 8 x bf16
typedef __attribute__((ext_vector_type(4))) float f32x4;    // MFMA accumulator / NT-loadable f32x4
typedef __attribute__((ext_vector_type(4))) unsigned short u16x4;

#define RL(v, i) __builtin_amdgcn_readlane(v, i)

__device__ __forceinline__ unsigned short f2bf(float f){
  unsigned int u = __builtin_bit_cast(unsigned int, f);
  return (unsigned short)((u + 0x7fffu + ((u >> 16) & 1u)) >> 16);   // RNE
}
__device__ __forceinline__ float bf2f(unsigned int lo){
  return __builtin_bit_cast(float, lo << 16);
}
__device__ __forceinline__ unsigned int packbf(float hi, float lo){
  return ((unsigned int)f2bf(hi) << 16) | f2bf(lo);
}

// ---- cast f32 -> bf16, 4 at a time; NT load (x is read exactly once) ----
__global__ void cast_bf16_vec(const float* __restrict__ in, unsigned short* __restrict__ out, int n4){
  int stride = gridDim.x * blockDim.x;
  for (int i = blockIdx.x * blockDim.x + threadIdx.x; i < n4; i += stride){
    f32x4 v = __builtin_nontemporal_load((const f32x4*)(in + (size_t)i * 4));
    u16x4 o;
    o[0] = f2bf(v[0]); o[1] = f2bf(v[1]); o[2] = f2bf(v[2]); o[3] = f2bf(v[3]);
    *(u16x4*)(out + (size_t)i * 4) = o;          // normal store: xb/wbb stay cached
  }
}

// ---- single atomic pass: histogram + per-edge rank ----
__global__ void hist_rank(const int* __restrict__ rel, const int* __restrict__ dst,
                          int* __restrict__ rowcnt, int* __restrict__ rank, int E){
  int stride = gridDim.x * blockDim.x;
  for (int i = blockIdx.x * blockDim.x + threadIdx.x; i < E; i += stride)
    rank[i] = atomicAdd(&rowcnt[(dst[i] << 3) | rel[i]], 1);
}

// ---- scan step 1: per-block (1024) sums ----
__launch_bounds__(1024)
__global__ void scan_block_sum(const int* __restrict__ rowcnt, int* __restrict__ bsum, int m){
  __shared__ int lds[16];
  int t = threadIdx.x;
  int idx = blockIdx.x * 1024 + t;
  int v = (idx < m) ? rowcnt[idx] : 0;
#pragma unroll
  for (int o = 32; o > 0; o >>= 1) v += __shfl_down(v, o);
  if ((t & 63) == 0) lds[t >> 6] = v;
  __syncthreads();
  if (t == 0){
    int s = 0;
#pragma unroll
    for (int w = 0; w < 16; ++w) s += lds[w];
    bsum[blockIdx.x] = s;
  }
}

// ---- scan step 2: PARALLEL exclusive scan of block sums (nb <= 1024) ----
__launch_bounds__(1024)
__global__ void scan_bsum_par(const int* __restrict__ bsum, int* __restrict__ bscan,
                              int nb, int* __restrict__ total_out){
  __shared__ int wsum[16];
  int t = threadIdx.x, lane = t & 63, wid = t >> 6;
  int v = (t < nb) ? bsum[t] : 0;
  int incl = v;
#pragma unroll
  for (int o = 1; o < 64; o <<= 1){
    int u = __shfl_up(incl, o);
    if (lane >= o) incl += u;
  }
  if (lane == 63) wsum[wid] = incl;
  __syncthreads();
  int woff = 0;
  for (int w0 = 0; w0 < wid; ++w0) woff += wsum[w0];
  if (t < nb) bscan[t] = woff + incl - v;
  if (t == nb - 1) *total_out = woff + incl;     // row_ptr[m] = E
}

// ---- scan step 3: wave-scan + cross-wave offset (1 barrier) ----
__launch_bounds__(1024)
__global__ void scan_final(const int* __restrict__ rowcnt, const int* __restrict__ bscan,
                           int* __restrict__ row_ptr, int m){
  __shared__ int wsum[16];
  int t = threadIdx.x, lane = t & 63, wid = t >> 6;
  int idx = blockIdx.x * 1024 + t;
  int v = (idx < m) ? rowcnt[idx] : 0;
  int incl = v;
#pragma unroll
  for (int o = 1; o < 64; o <<= 1){
    int u = __shfl_up(incl, o);
    if (lane >= o) incl += u;
  }
  if (lane == 63) wsum[wid] = incl;
  __syncthreads();
  int woff = bscan[blockIdx.x];
  for (int w0 = 0; w0 < wid; ++w0) woff += wsum[w0];
  if (idx < m) row_ptr[idx] = woff + incl - v;   // exclusive
}

// ---- atomic-free bucket write: pos = row_ptr[key] + rank ----
__global__ void scatter_pos(const int* __restrict__ rel, const int* __restrict__ src,
                            const int* __restrict__ dst, const int* __restrict__ rank,
                            const int* __restrict__ row_ptr, int* __restrict__ payload, int E){
  int stride = gridDim.x * blockDim.x;
  for (int i = blockIdx.x * blockDim.x + threadIdx.x; i < E; i += stride){
    int key = (dst[i] << 3) | rel[i];
    payload[row_ptr[key] + rank[i]] = src[i];
  }
}

// ---- 2 waves per node (4 relations each): flat quad-batched window walk,
//      scalar-branch routing into 4 static accumulators, NT h2 stores ----
__launch_bounds__(256)
__global__ void row_agg(const unsigned short* __restrict__ xb,
                        const int* __restrict__ row_ptr8,
                        const int* __restrict__ payload,
                        unsigned short* __restrict__ h2, int n){
  int wv   = (blockIdx.x * 256 + threadIdx.x) >> 6;
  int lane = threadIdx.x & 63;
  int d    = wv >> 1;
  int half = wv & 1;                               // relations 4*half .. 4*half+3
  if (d >= n) return;

  int p5 = 0;
  if (lane < 5) p5 = row_ptr8[(d << 3) + (half << 2) + lane];
  int b0  = RL(p5, 0);
  int o1  = RL(p5, 1) - b0;                        // all SGPRs -> scalar control flow
  int o2  = RL(p5, 2) - b0;
  int o3  = RL(p5, 3) - b0;
  int cnt = RL(p5, 4) - b0;

  float ax0=0.f,ay0=0.f,ax1=0.f,ay1=0.f,ax2=0.f,ay2=0.f,ax3=0.f,ay3=0.f;

#define ROUTE(VV, IDX) { \
    float lo = bf2f((VV) & 0xffffu), hi = bf2f((VV) >> 16); \
    if ((IDX) < o1)      { ax0 += lo; ay0 += hi; } \
    else if ((IDX) < o2) { ax1 += lo; ay1 += hi; } \
    else if ((IDX) < o3) { ax2 += lo; ay2 += hi; } \
    else                 { ax3 += lo; ay3 += hi; } }

  if (cnt <= 64){                                  // fast path: one payload window
    int pl = payload[b0 + lane];                   // (reads past E land in row_ptr pad)
    int e = 0;
    for (; e + 4 <= cnt; e += 4){                  // 4 loads in flight before any use
      int s0 = RL(pl, e);
      int s1 = RL(pl, e + 1);
      int s2 = RL(pl, e + 2);
      int s3 = RL(pl, e + 3);
      unsigned int v0 = ((const unsigned int*)(xb + ((size_t)s0 << 7)))[lane];
      unsigned int v1 = ((const unsigned int*)(xb + ((size_t)s1 << 7)))[lane];
      unsigned int v2 = ((const unsigned int*)(xb + ((size_t)s2 << 7)))[lane];
      unsigned int v3 = ((const unsigned int*)(xb + ((size_t)s3 << 7)))[lane];
      ROUTE(v0, e)
      ROUTE(v1, e + 1)
      ROUTE(v2, e + 2)
      ROUTE(v3, e + 3)
    }
    for (; e < cnt; ++e){                          // tail (<=3 edges)
      int s = RL(pl, e);
      unsigned int v = ((const unsigned int*)(xb + ((size_t)s << 7)))[lane];
      ROUTE(v, e)
    }
  } else {                                         // rare fat node: serial path
    for (int e = 0; e < cnt; ++e){
      int s = __builtin_amdgcn_readfirstlane(payload[b0 + e]);
      unsigned int v = ((const unsigned int*)(xb + ((size_t)s << 7)))[lane];
      ROUTE(v, e)
    }
  }
#undef ROUTE

  int d0 = o1, d1 = o2 - o1, d2 = o3 - o2, d3 = cnt - o3;
  float s0f = d0 ? 1.f / (float)d0 : 0.f;
  float s1f = d1 ? 1.f / (float)d1 : 0.f;
  float s2f = d2 ? 1.f / (float)d2 : 0.f;
  float s3f = d3 ? 1.f / (float)d3 : 0.f;
  unsigned int* hp = (unsigned int*)h2 + ((size_t)d << 9) + (half << 8) + lane;
  __builtin_nontemporal_store(packbf(ay0 * s0f, ax0 * s0f), hp);
  __builtin_nontemporal_store(packbf(ay1 * s1f, ax1 * s1f), hp + 64);
  __builtin_nontemporal_store(packbf(ay2 * s2f, ax2 * s2f), hp + 128);
  __builtin_nontemporal_store(packbf(ay3 * s3f, ax3 * s3f), hp + 192);
}

// ---- out[d][j] = relu( sum_r sum_kk h2[d][r*128+kk] * W[r][j][kk] ) ----
// 128x128 block tile, 4 waves in 2x2 grid, A+B LDS-staged per r; NT on h2/out streams
__launch_bounds__(256)
__global__ void gemm_out(const unsigned short* __restrict__ h2,
                         const unsigned short* __restrict__ wbb,
                         float* __restrict__ out, int n){
  __shared__ __align__(16) unsigned short lds_a[128 * LDB];   // 34.8 KB
  __shared__ __align__(16) unsigned short lds_b[128 * LDB];   // 34.8 KB
  const int t = threadIdx.x;
  const int wave = t >> 6, lane = t & 63;
  const int wr = wave >> 1, wc = wave & 1;        // 2x2 wave grid
  const int dbase = blockIdx.x * 128;
  const int frow = lane & 15, kb = lane >> 4;

  f32x4 acc[4][4];
#pragma unroll
  for (int rt = 0; rt < 4; ++rt)
#pragma unroll
    for (int jt = 0; jt < 4; ++jt)
      acc[rt][jt] = (f32x4){0.f, 0.f, 0.f, 0.f};

  for (int r = 0; r < RR; ++r){
    __syncthreads();                               // protect LDS from prev-iter readers
    // stage A chunk: 128 rows x 256B, NT (h2 is read exactly once chip-wide)
#pragma unroll
    for (int p = 0; p < 8; ++p){
      int q = p * 256 + t;
      int row = q >> 4, col = q & 15;
      int gr = dbase + row; if (gr >= n) gr = n - 1;
      short8 vv = __builtin_nontemporal_load(
          (const short8*)(h2 + (size_t)gr * KTOT + r * ED + col * 8));
      *(short8*)&lds_a[row * LDB + col * 8] = vv;
    }
    // stage B chunk: W[r], 32 KB fully contiguous (normal: keep L2-hot)
    const unsigned short* wp = wbb + (size_t)r * ED * ED;
#pragma unroll
    for (int p = 0; p < 8; ++p){
      int q = p * 256 + t;
      int row = q >> 4, col = q & 15;
      *(short8*)&lds_b[row * LDB + col * 8] = *(const short8*)(wp + row * ED + col * 8);
    }
    __syncthreads();

    short8 a[4][4], b[4][4];
#pragma unroll
    for (int rt = 0; rt < 4; ++rt)
#pragma unroll
      for (int ks = 0; ks < 4; ++ks)
        a[rt][ks] = *(const short8*)&lds_a[(wr * 64 + rt * 16 + frow) * LDB + ks * 32 + kb * 8];
#pragma unroll
    for (int jt = 0; jt < 4; ++jt)
#pragma unroll
      for (int ks = 0; ks < 4; ++ks)
        b[jt][ks] = *(const short8*)&lds_b[(wc * 64 + jt * 16 + frow) * LDB + ks * 32 + kb * 8];
#pragma unroll
    for (int rt = 0; rt < 4; ++rt)
#pragma unroll
      for (int jt = 0; jt < 4; ++jt)
#pragma unroll
        for (int ks = 0; ks < 4; ++ks)
          acc[rt][jt] = __builtin_amdgcn_mfma_f32_16x16x32_bf16(a[rt][ks], b[jt][ks], acc[rt][jt], 0, 0, 0);
  }

  // D layout: col = lane&15, row = (lane>>4)*4 + reg
  const int drow = (lane >> 4) * 4;
  const int dcol = lane & 15;
#pragma unroll
  for (int rt = 0; rt < 4; ++rt)
#pragma unroll
    for (int jt = 0; jt < 4; ++jt)
#pragma unroll
      for (int reg = 0; reg < 4; ++reg){
        int i = dbase + wr * 64 + rt * 16 + drow + reg;
        if (i < n)
          __builtin_nontemporal_store(fmaxf(acc[rt][jt][reg], 0.f),
                                      &out[(size_t)i * ED + wc * 64 + jt * 16 + dcol]);
      }
}

extern "C" void kernel_launch(void* const* d_in, const int* in_sizes, int n_in,
                              void* d_out, int out_size, void* d_ws, size_t ws_size,
                              hipStream_t stream){
  const float* x  = (const float*)d_in[0];
  const float* w  = (const float*)d_in[1];
  const int* erel = (const int*)d_in[2];
  const int* esrc = (const int*)d_in[3];
  const int* edst = (const int*)d_in[4];
  float* out = (float*)d_out;

  const int n = in_sizes[0] / ED;          // 100000
  const int E = in_sizes[2];               // 1600000
  const int m = n * RR;                    // 800000 CSR rows
  const int NB = (m + 1023) / 1024;        // 782 (must be <= 1024)

  // ---- workspace layout (256B-aligned segments) ----
  char* ws = (char*)d_ws;
  size_t off = 0;
  auto alloc = [&](size_t bytes) -> char* {
    char* p = ws + off;
    off += (bytes + 255) & ~(size_t)255;
    return p;
  };
  unsigned short* h2      = (unsigned short*)alloc((size_t)n * KTOT * 2);   // 204.8 MB
  unsigned short* xb      = (unsigned short*)alloc((size_t)n * ED * 2);     // 25.6 MB
  unsigned short* wbb     = (unsigned short*)alloc((size_t)RR * ED * ED * 2); // 256 KB
  int*            payload = (int*)alloc((size_t)E * 4);                     // 6.4 MB
  int*            row_ptr = (int*)alloc((size_t)(m + 1) * 4);               // 3.2 MB (pads payload OOB prefetch)
  int*            rowcnt  = (int*)alloc((size_t)m * 4);
  int*            rank    = (int*)alloc((size_t)E * 4);                     // 6.4 MB
  int*            bsum    = (int*)alloc((size_t)NB * 4);
  int*            bscan   = (int*)alloc((size_t)NB * 4);
  if (off > ws_size || NB > 1024) return;

  (void)hipMemsetAsync(rowcnt, 0, (size_t)m * 4, stream);

  cast_bf16_vec<<<2048, 256, 0, stream>>>(x, xb, n * ED / 4);
  cast_bf16_vec<<<128, 256, 0, stream>>>(w, wbb, RR * ED * ED / 4);
  hist_rank    <<<2048, 256, 0, stream>>>(erel, edst, rowcnt, rank, E);
  scan_block_sum<<<NB, 1024, 0, stream>>>(rowcnt, bsum, m);
  scan_bsum_par<<<1, 1024, 0, stream>>>(bsum, bscan, NB, row_ptr + m);
  scan_final   <<<NB, 1024, 0, stream>>>(rowcnt, bscan, row_ptr, m);
  scatter_pos  <<<2048, 256, 0, stream>>>(erel, esrc, edst, rank, row_ptr, payload, E);
  row_agg      <<<(2 * n + 3) / 4, 256, 0, stream>>>(xb, row_ptr, payload, h2, n);
  gemm_out     <<<(n + 127) / 128, 256, 0, stream>>>(h2, wbb, out, n);
}

// Round 9
// 284.379 us; speedup vs baseline: 2.4296x; 1.0305x over previous
//
#include <hip/hip_runtime.h>
#include <hip/hip_bf16.h>

#define ED 128
#define RR 8
#define KTOT (RR * ED)   // 1024
#define LDB 136          // LDS row stride in shorts (128 data + 8 pad) -> 68 dwords, 2-way free

typedef __attribute__((ext_vector_type(8))) short short8;   // 8 x bf16
typedef __attribute__((ext_vector_type(4))) float f32x4;    // MFMA accumulator / NT-loadable f32x4
typedef __attribute__((ext_vector_type(4))) unsigned short u16x4;

#define RL(v, i) __builtin_amdgcn_readlane(v, i)

__device__ __forceinline__ unsigned short f2bf(float f){
  unsigned int u = __builtin_bit_cast(unsigned int, f);
  return (unsigned short)((u + 0x7fffu + ((u >> 16) & 1u)) >> 16);   // RNE
}
__device__ __forceinline__ float bf2f(unsigned int lo){
  return __builtin_bit_cast(float, lo << 16);
}
__device__ __forceinline__ unsigned int packbf(float hi, float lo){
  return ((unsigned int)f2bf(hi) << 16) | f2bf(lo);
}

// ---- cast f32 -> bf16, 4 at a time; NT load (x is read exactly once) ----
__global__ void cast_bf16_vec(const float* __restrict__ in, unsigned short* __restrict__ out, int n4){
  int stride = gridDim.x * blockDim.x;
  for (int i = blockIdx.x * blockDim.x + threadIdx.x; i < n4; i += stride){
    f32x4 v = __builtin_nontemporal_load((const f32x4*)(in + (size_t)i * 4));
    u16x4 o;
    o[0] = f2bf(v[0]); o[1] = f2bf(v[1]); o[2] = f2bf(v[2]); o[3] = f2bf(v[3]);
    *(u16x4*)(out + (size_t)i * 4) = o;          // normal store: xb/wbb stay cached
  }
}

// ---- single atomic pass: histogram + per-edge rank ----
__global__ void hist_rank(const int* __restrict__ rel, const int* __restrict__ dst,
                          int* __restrict__ rowcnt, int* __restrict__ rank, int E){
  int stride = gridDim.x * blockDim.x;
  for (int i = blockIdx.x * blockDim.x + threadIdx.x; i < E; i += stride)
    rank[i] = atomicAdd(&rowcnt[(dst[i] << 3) | rel[i]], 1);
}

// ---- scan step 1: per-block (1024) sums ----
__launch_bounds__(1024)
__global__ void scan_block_sum(const int* __restrict__ rowcnt, int* __restrict__ bsum, int m){
  __shared__ int lds[16];
  int t = threadIdx.x;
  int idx = blockIdx.x * 1024 + t;
  int v = (idx < m) ? rowcnt[idx] : 0;
#pragma unroll
  for (int o = 32; o > 0; o >>= 1) v += __shfl_down(v, o);
  if ((t & 63) == 0) lds[t >> 6] = v;
  __syncthreads();
  if (t == 0){
    int s = 0;
#pragma unroll
    for (int w = 0; w < 16; ++w) s += lds[w];
    bsum[blockIdx.x] = s;
  }
}

// ---- scan step 2: PARALLEL exclusive scan of block sums (nb <= 1024) ----
__launch_bounds__(1024)
__global__ void scan_bsum_par(const int* __restrict__ bsum, int* __restrict__ bscan,
                              int nb, int* __restrict__ total_out){
  __shared__ int wsum[16];
  int t = threadIdx.x, lane = t & 63, wid = t >> 6;
  int v = (t < nb) ? bsum[t] : 0;
  int incl = v;
#pragma unroll
  for (int o = 1; o < 64; o <<= 1){
    int u = __shfl_up(incl, o);
    if (lane >= o) incl += u;
  }
  if (lane == 63) wsum[wid] = incl;
  __syncthreads();
  int woff = 0;
  for (int w0 = 0; w0 < wid; ++w0) woff += wsum[w0];
  if (t < nb) bscan[t] = woff + incl - v;
  if (t == nb - 1) *total_out = woff + incl;     // row_ptr[m] = E
}

// ---- scan step 3: wave-scan + cross-wave offset (1 barrier) ----
__launch_bounds__(1024)
__global__ void scan_final(const int* __restrict__ rowcnt, const int* __restrict__ bscan,
                           int* __restrict__ row_ptr, int m){
  __shared__ int wsum[16];
  int t = threadIdx.x, lane = t & 63, wid = t >> 6;
  int idx = blockIdx.x * 1024 + t;
  int v = (idx < m) ? rowcnt[idx] : 0;
  int incl = v;
#pragma unroll
  for (int o = 1; o < 64; o <<= 1){
    int u = __shfl_up(incl, o);
    if (lane >= o) incl += u;
  }
  if (lane == 63) wsum[wid] = incl;
  __syncthreads();
  int woff = bscan[blockIdx.x];
  for (int w0 = 0; w0 < wid; ++w0) woff += wsum[w0];
  if (idx < m) row_ptr[idx] = woff + incl - v;   // exclusive
}

// ---- atomic-free bucket write: pos = row_ptr[key] + rank ----
__global__ void scatter_pos(const int* __restrict__ rel, const int* __restrict__ src,
                            const int* __restrict__ dst, const int* __restrict__ rank,
                            const int* __restrict__ row_ptr, int* __restrict__ payload, int E){
  int stride = gridDim.x * blockDim.x;
  for (int i = blockIdx.x * blockDim.x + threadIdx.x; i < E; i += stride){
    int key = (dst[i] << 3) | rel[i];
    payload[row_ptr[key] + rank[i]] = src[i];
  }
}

// ---- 1 wave per node (all 8 relations): flat window walk, 8 loads in flight,
//      binary scalar routing into 8 static accumulators, NT h2 stores ----
__launch_bounds__(256)
__global__ void row_agg(const unsigned short* __restrict__ xb,
                        const int* __restrict__ row_ptr8,
                        const int* __restrict__ payload,
                        unsigned short* __restrict__ h2, int n){
  int d    = (blockIdx.x * 256 + threadIdx.x) >> 6;
  int lane = threadIdx.x & 63;
  if (d >= n) return;

  int p9 = 0;
  if (lane < 9) p9 = row_ptr8[(d << 3) + lane];    // 9 segment boundaries
  int b0  = RL(p9, 0);
  int o1  = RL(p9, 1) - b0;                        // all SGPRs -> scalar control flow
  int o2  = RL(p9, 2) - b0;
  int o3  = RL(p9, 3) - b0;
  int o4  = RL(p9, 4) - b0;
  int o5  = RL(p9, 5) - b0;
  int o6  = RL(p9, 6) - b0;
  int o7  = RL(p9, 7) - b0;
  int cnt = RL(p9, 8) - b0;

  float ax0=0.f,ay0=0.f,ax1=0.f,ay1=0.f,ax2=0.f,ay2=0.f,ax3=0.f,ay3=0.f;
  float ax4=0.f,ay4=0.f,ax5=0.f,ay5=0.f,ax6=0.f,ay6=0.f,ax7=0.f,ay7=0.f;

#define ROUTE(VV, IDX) { \
    float lo = bf2f((VV) & 0xffffu), hi = bf2f((VV) >> 16); \
    if ((IDX) < o4){ \
      if ((IDX) < o2){ if ((IDX) < o1){ ax0+=lo; ay0+=hi; } else { ax1+=lo; ay1+=hi; } } \
      else           { if ((IDX) < o3){ ax2+=lo; ay2+=hi; } else { ax3+=lo; ay3+=hi; } } \
    } else { \
      if ((IDX) < o6){ if ((IDX) < o5){ ax4+=lo; ay4+=hi; } else { ax5+=lo; ay5+=hi; } } \
      else           { if ((IDX) < o7){ ax6+=lo; ay6+=hi; } else { ax7+=lo; ay7+=hi; } } \
    } }

  if (cnt <= 64){                                  // fast path: one payload window
    int pl = payload[b0 + lane];                   // (reads past E land in row_ptr pad)
    int e = 0;
    for (; e + 8 <= cnt; e += 8){                  // 8 loads in flight before any use
      int s0 = RL(pl, e);
      int s1 = RL(pl, e + 1);
      int s2 = RL(pl, e + 2);
      int s3 = RL(pl, e + 3);
      int s4 = RL(pl, e + 4);
      int s5 = RL(pl, e + 5);
      int s6 = RL(pl, e + 6);
      int s7 = RL(pl, e + 7);
      unsigned int v0 = ((const unsigned int*)(xb + ((size_t)s0 << 7)))[lane];
      unsigned int v1 = ((const unsigned int*)(xb + ((size_t)s1 << 7)))[lane];
      unsigned int v2 = ((const unsigned int*)(xb + ((size_t)s2 << 7)))[lane];
      unsigned int v3 = ((const unsigned int*)(xb + ((size_t)s3 << 7)))[lane];
      unsigned int v4 = ((const unsigned int*)(xb + ((size_t)s4 << 7)))[lane];
      unsigned int v5 = ((const unsigned int*)(xb + ((size_t)s5 << 7)))[lane];
      unsigned int v6 = ((const unsigned int*)(xb + ((size_t)s6 << 7)))[lane];
      unsigned int v7 = ((const unsigned int*)(xb + ((size_t)s7 << 7)))[lane];
      ROUTE(v0, e)
      ROUTE(v1, e + 1)
      ROUTE(v2, e + 2)
      ROUTE(v3, e + 3)
      ROUTE(v4, e + 4)
      ROUTE(v5, e + 5)
      ROUTE(v6, e + 6)
      ROUTE(v7, e + 7)
    }
    for (; e < cnt; ++e){                          // tail (<=7 edges)
      int s = RL(pl, e);
      unsigned int v = ((const unsigned int*)(xb + ((size_t)s << 7)))[lane];
      ROUTE(v, e)
    }
  } else {                                         // rare fat node: serial path
    for (int e = 0; e < cnt; ++e){
      int s = __builtin_amdgcn_readfirstlane(payload[b0 + e]);
      unsigned int v = ((const unsigned int*)(xb + ((size_t)s << 7)))[lane];
      ROUTE(v, e)
    }
  }
#undef ROUTE

  int c0 = o1, c1 = o2 - o1, c2 = o3 - o2, c3 = o4 - o3;
  int c4 = o5 - o4, c5 = o6 - o5, c6 = o7 - o6, c7 = cnt - o7;
  unsigned int* hp = (unsigned int*)h2 + ((size_t)d << 9) + lane;
  float sc;
  sc = c0 ? 1.f / (float)c0 : 0.f; __builtin_nontemporal_store(packbf(ay0*sc, ax0*sc), hp);
  sc = c1 ? 1.f / (float)c1 : 0.f; __builtin_nontemporal_store(packbf(ay1*sc, ax1*sc), hp + 64);
  sc = c2 ? 1.f / (float)c2 : 0.f; __builtin_nontemporal_store(packbf(ay2*sc, ax2*sc), hp + 128);
  sc = c3 ? 1.f / (float)c3 : 0.f; __builtin_nontemporal_store(packbf(ay3*sc, ax3*sc), hp + 192);
  sc = c4 ? 1.f / (float)c4 : 0.f; __builtin_nontemporal_store(packbf(ay4*sc, ax4*sc), hp + 256);
  sc = c5 ? 1.f / (float)c5 : 0.f; __builtin_nontemporal_store(packbf(ay5*sc, ax5*sc), hp + 320);
  sc = c6 ? 1.f / (float)c6 : 0.f; __builtin_nontemporal_store(packbf(ay6*sc, ax6*sc), hp + 384);
  sc = c7 ? 1.f / (float)c7 : 0.f; __builtin_nontemporal_store(packbf(ay7*sc, ax7*sc), hp + 448);
}

// ---- out[d][j] = relu( sum_r sum_kk h2[d][r*128+kk] * W[r][j][kk] ) ----
// 128x128 block tile, 4 waves in 2x2 grid, A+B LDS-staged per r,
// register-prefetch of next r chunk overlapped with MFMA; NT on h2/out streams
__launch_bounds__(256)
__global__ void gemm_out(const unsigned short* __restrict__ h2,
                         const unsigned short* __restrict__ wbb,
                         float* __restrict__ out, int n){
  __shared__ __align__(16) unsigned short lds_a[128 * LDB];   // 34.8 KB
  __shared__ __align__(16) unsigned short lds_b[128 * LDB];   // 34.8 KB
  const int t = threadIdx.x;
  const int wave = t >> 6, lane = t & 63;
  const int wr = wave >> 1, wc = wave & 1;        // 2x2 wave grid
  const int dbase = blockIdx.x * 128;
  const int frow = lane & 15, kb = lane >> 4;

  f32x4 acc[4][4];
#pragma unroll
  for (int rt = 0; rt < 4; ++rt)
#pragma unroll
    for (int jt = 0; jt < 4; ++jt)
      acc[rt][jt] = (f32x4){0.f, 0.f, 0.f, 0.f};

  short8 pa[8], pb[8];
  // prefetch chunk r = 0 into registers
#pragma unroll
  for (int p = 0; p < 8; ++p){
    int q = p * 256 + t;
    int row = q >> 4, col = q & 15;
    int gr = dbase + row; if (gr >= n) gr = n - 1;
    pa[p] = __builtin_nontemporal_load((const short8*)(h2 + (size_t)gr * KTOT + col * 8));
    pb[p] = *(const short8*)(wbb + row * ED + col * 8);
  }

  for (int r = 0; r < RR; ++r){
    __syncthreads();                               // prev-iter LDS readers done
    // commit prefetched chunk to LDS
#pragma unroll
    for (int p = 0; p < 8; ++p){
      int q = p * 256 + t;
      int row = q >> 4, col = q & 15;
      *(short8*)&lds_a[row * LDB + col * 8] = pa[p];
      *(short8*)&lds_b[row * LDB + col * 8] = pb[p];
    }
    __syncthreads();

    // issue next chunk's global loads; latency hides under the MFMA block below
    if (r + 1 < RR){
#pragma unroll
      for (int p = 0; p < 8; ++p){
        int q = p * 256 + t;
        int row = q >> 4, col = q & 15;
        int gr = dbase + row; if (gr >= n) gr = n - 1;
        pa[p] = __builtin_nontemporal_load(
            (const short8*)(h2 + (size_t)gr * KTOT + (r + 1) * ED + col * 8));
        pb[p] = *(const short8*)(wbb + (size_t)(r + 1) * ED * ED + row * ED + col * 8);
      }
    }

    short8 a[4][4], b[4][4];
#pragma unroll
    for (int rt = 0; rt < 4; ++rt)
#pragma unroll
      for (int ks = 0; ks < 4; ++ks)
        a[rt][ks] = *(const short8*)&lds_a[(wr * 64 + rt * 16 + frow) * LDB + ks * 32 + kb * 8];
#pragma unroll
    for (int jt = 0; jt < 4; ++jt)
#pragma unroll
      for (int ks = 0; ks < 4; ++ks)
        b[jt][ks] = *(const short8*)&lds_b[(wc * 64 + jt * 16 + frow) * LDB + ks * 32 + kb * 8];
#pragma unroll
    for (int rt = 0; rt < 4; ++rt)
#pragma unroll
      for (int jt = 0; jt < 4; ++jt)
#pragma unroll
        for (int ks = 0; ks < 4; ++ks)
          acc[rt][jt] = __builtin_amdgcn_mfma_f32_16x16x32_bf16(a[rt][ks], b[jt][ks], acc[rt][jt], 0, 0, 0);
  }

  // D layout: col = lane&15, row = (lane>>4)*4 + reg
  const int drow = (lane >> 4) * 4;
  const int dcol = lane & 15;
#pragma unroll
  for (int rt = 0; rt < 4; ++rt)
#pragma unroll
    for (int jt = 0; jt < 4; ++jt)
#pragma unroll
      for (int reg = 0; reg < 4; ++reg){
        int i = dbase + wr * 64 + rt * 16 + drow + reg;
        if (i < n)
          __builtin_nontemporal_store(fmaxf(acc[rt][jt][reg], 0.f),
                                      &out[(size_t)i * ED + wc * 64 + jt * 16 + dcol]);
      }
}

extern "C" void kernel_launch(void* const* d_in, const int* in_sizes, int n_in,
                              void* d_out, int out_size, void* d_ws, size_t ws_size,
                              hipStream_t stream){
  const float* x  = (const float*)d_in[0];
  const float* w  = (const float*)d_in[1];
  const int* erel = (const int*)d_in[2];
  const int* esrc = (const int*)d_in[3];
  const int* edst = (const int*)d_in[4];
  float* out = (float*)d_out;

  const int n = in_sizes[0] / ED;          // 100000
  const int E = in_sizes[2];               // 1600000
  const int m = n * RR;                    // 800000 CSR rows
  const int NB = (m + 1023) / 1024;        // 782 (must be <= 1024)

  // ---- workspace layout (256B-aligned segments) ----
  char* ws = (char*)d_ws;
  size_t off = 0;
  auto alloc = [&](size_t bytes) -> char* {
    char* p = ws + off;
    off += (bytes + 255) & ~(size_t)255;
    return p;
  };
  unsigned short* h2      = (unsigned short*)alloc((size_t)n * KTOT * 2);   // 204.8 MB
  unsigned short* xb      = (unsigned short*)alloc((size_t)n * ED * 2);     // 25.6 MB
  unsigned short* wbb     = (unsigned short*)alloc((size_t)RR * ED * ED * 2); // 256 KB
  int*            payload = (int*)alloc((size_t)E * 4);                     // 6.4 MB
  int*            row_ptr = (int*)alloc((size_t)(m + 1) * 4);               // 3.2 MB (pads payload OOB prefetch)
  int*            rowcnt  = (int*)alloc((size_t)m * 4);
  int*            rank    = (int*)alloc((size_t)E * 4);                     // 6.4 MB
  int*            bsum    = (int*)alloc((size_t)NB * 4);
  int*            bscan   = (int*)alloc((size_t)NB * 4);
  if (off > ws_size || NB > 1024) return;

  (void)hipMemsetAsync(rowcnt, 0, (size_t)m * 4, stream);

  cast_bf16_vec<<<2048, 256, 0, stream>>>(x, xb, n * ED / 4);
  cast_bf16_vec<<<128, 256, 0, stream>>>(w, wbb, RR * ED * ED / 4);
  hist_rank    <<<2048, 256, 0, stream>>>(erel, edst, rowcnt, rank, E);
  scan_block_sum<<<NB, 1024, 0, stream>>>(rowcnt, bsum, m);
  scan_bsum_par<<<1, 1024, 0, stream>>>(bsum, bscan, NB, row_ptr + m);
  scan_final   <<<NB, 1024, 0, stream>>>(rowcnt, bscan, row_ptr, m);
  scatter_pos  <<<2048, 256, 0, stream>>>(erel, esrc, edst, rank, row_ptr, payload, E);
  row_agg      <<<(n + 3) / 4, 256, 0, stream>>>(xb, row_ptr, payload, h2, n);
  gemm_out     <<<(n + 127) / 128, 256, 0, stream>>>(h2, wbb, out, n);
}